// Round 2
// baseline (2654397.070 us; speedup 1.0000x reference)
//
#include <hip/hip_runtime.h>
#include <math.h>

// ---------------------------------------------------------------------------
// Persistent-kernel trainer for the 16384-step sequential MLP scan.
// All weights live in LDS, partitioned by ownership:
//   WG g owns w1 columns [4g,4g+4), w2 columns [4g,4g+4), w3 rows [4g,4g+4).
// Cross-WG traffic (agent-scope, MALL-coherent): u (x_t·W1_{t-1}), o1 partials,
// a3 partial sums (64), and norm scalar partials. 3 custom grid syncs / step.
// ---------------------------------------------------------------------------

#define NSTEP 16384
#define INDIM 1024
#define HID   1024
#define OUTD  64
#define LR    0.01f
#define EPSN  1e-8f

#define NWG   256
#define TPB   512
#define CW    4      // w1/w2 columns (and w3 rows) per WG

// workspace layout (float indices)
#define OFF_ARRIVE   0                         // 256 ints
#define OFF_RELEASE  512                       // 1 int
#define OFF_QPART    1024                      // NWG*HID
#define OFF_U        (OFF_QPART + NWG*HID)     // HID
#define OFF_O1RAW    (OFF_U + HID)             // HID
#define OFF_P3       (OFF_O1RAW + HID)         // 2*16*64
#define OFF_ACC      (OFF_P3 + 2*16*64)        // 2*16*8
#define OFF_SDOT     (OFF_ACC + 2*16*8)        // NSTEP
#define OFF_NORMX    (OFF_SDOT + NSTEP)        // NSTEP

// ACC scalar slots: 0 m1, 1 m2, 2 m3, 3 dot_d2o2, 4 sum_o2sq, 5 sum_B2sq, 6 sum_a2sq

__device__ __forceinline__ float dload(const float* p){
  return __hip_atomic_load(p, __ATOMIC_RELAXED, __HIP_MEMORY_SCOPE_AGENT);
}
__device__ __forceinline__ void dstore(float* p, float v){
  __hip_atomic_store(p, v, __ATOMIC_RELAXED, __HIP_MEMORY_SCOPE_AGENT);
}
__device__ __forceinline__ float wredf(float v){
  #pragma unroll
  for (int m = 32; m; m >>= 1) v += __shfl_xor(v, m, 64);
  return v;
}
__device__ __forceinline__ float sigf(float z){ return 1.f/(1.f+expf(-z)); }

__device__ void gsync(int* arrive, int* release, int e, int wg){
  __builtin_amdgcn_fence(__ATOMIC_RELEASE, "agent");
  __syncthreads();
  if (threadIdx.x == 0)
    __hip_atomic_store(&arrive[wg], e, __ATOMIC_RELEASE, __HIP_MEMORY_SCOPE_AGENT);
  if (wg == 0){
    if (threadIdx.x < NWG){
      while (__hip_atomic_load(&arrive[threadIdx.x], __ATOMIC_ACQUIRE,
                               __HIP_MEMORY_SCOPE_AGENT) < e)
        __builtin_amdgcn_s_sleep(1);
    }
    __syncthreads();
    if (threadIdx.x == 0)
      __hip_atomic_store(release, e, __ATOMIC_RELEASE, __HIP_MEMORY_SCOPE_AGENT);
  }
  if (threadIdx.x == 0){
    while (__hip_atomic_load(release, __ATOMIC_ACQUIRE,
                             __HIP_MEMORY_SCOPE_AGENT) < e)
      __builtin_amdgcn_s_sleep(1);
  }
  __syncthreads();
  __builtin_amdgcn_fence(__ATOMIC_ACQUIRE, "agent");
}

// ---------------------------------------------------------------------------
// init kernel: precompute sdot[t] = x_t . x_{t-1}, normx[t] = |x_t|^2 ;
// block 0 additionally zeroes flags/accumulators and seeds t=0 scalars.
// ---------------------------------------------------------------------------
__global__ __launch_bounds__(64) void bp_init(const float* __restrict__ x, float* wsf){
  const int t = blockIdx.x, tid = threadIdx.x;
  const float* xt = x + (size_t)t * INDIM;
  const float* xp = x + (size_t)(t > 0 ? t - 1 : 0) * INDIM;
  float sp = 0.f, nx = 0.f;
  #pragma unroll
  for (int e = 0; e < INDIM/64; e++){
    int i = tid + 64*e; float a = xt[i];
    nx += a*a; sp += a*xp[i];
  }
  sp = wredf(sp); nx = wredf(nx);
  if (tid == 0){ wsf[OFF_SDOT + t] = (t > 0) ? sp : 0.f; wsf[OFF_NORMX + t] = nx; }
  if (blockIdx.x == 0){
    int* wsi = (int*)wsf;
    for (int i = tid; i < 256; i += 64) wsi[OFF_ARRIVE + i] = 0;
    if (tid == 0) wsi[OFF_RELEASE] = 0;
    for (int i = tid; i < HID;      i += 64) wsf[OFF_O1RAW + i] = 0.f;
    for (int i = tid; i < 2*16*64;  i += 64) wsf[OFF_P3 + i]    = 0.f;
    for (int i = tid; i < 2*16*8;   i += 64) wsf[OFF_ACC + i]   = 0.f;
    __syncthreads();
    if (tid == 0){
      float* acc1 = wsf + OFF_ACC + 16*8;   // parity 1, bank 0
      acc1[0] = 1.f; acc1[1] = 1.f; acc1[2] = 1.f; acc1[5] = 1.f; // m1,m2,m3,sumB2sq "prev"
    }
  }
}

// ---------------------------------------------------------------------------
// persistent training kernel
// ---------------------------------------------------------------------------
__global__ __launch_bounds__(TPB) void bp_train(
    const float* __restrict__ xdat, const float* __restrict__ tgt,
    const float* __restrict__ w1g, const float* __restrict__ b1g,
    const float* __restrict__ w2g, const float* __restrict__ b2g,
    const float* __restrict__ w3g, const float* __restrict__ b3g,
    float* __restrict__ out, float* wsf)
{
  __shared__ float s1[CW*HID];      // w1 columns (col-major per column)
  __shared__ float s2[CW*HID];      // w2 columns
  __shared__ float s3[CW*OUTD];     // w3 rows
  __shared__ float a1b[2][HID];     // a1 ping-pong (redundant, all WGs identical)
  __shared__ float d1s[HID];        // d1 (pre-activation of layer 1), redundant
  __shared__ float b1s[HID];        // b1 replica, redundant
  __shared__ float o1f[HID];        // o1 of previous step, redundant
  __shared__ float d3b[2][OUTD];    // d3 ping-pong, redundant
  __shared__ float p3r[OUTD];       // raw a2.W3 dot of previous step, redundant
  __shared__ float b3s[OUTD];       // b3 replica, redundant
  __shared__ float o2l[CW], d2l[CW], b2l[CW];
  __shared__ float a2b[2][CW];
  __shared__ float ascr[256];

  const int tid = threadIdx.x;
  const int wg  = blockIdx.x;
  int*   arrive  = (int*)wsf + OFF_ARRIVE;
  int*   release = (int*)wsf + OFF_RELEASE;
  float* QP  = wsf + OFF_QPART;
  float* U   = wsf + OFF_U;
  float* O1R = wsf + OFF_O1RAW;
  float* P3  = wsf + OFF_P3;
  float* AC  = wsf + OFF_ACC;
  float* SD  = wsf + OFF_SDOT;
  float* NX  = wsf + OFF_NORMX;
  const int bank = wg & 15;

  // ---- load owned slices + replicas, zero state ----
  for (int v = tid; v < CW*HID; v += TPB){
    int j = v & (CW-1); int i = v >> 2;
    s1[j*HID + i] = w1g[(size_t)i*HID + wg*CW + j];
    s2[j*HID + i] = w2g[(size_t)i*HID + wg*CW + j];
  }
  for (int v = tid; v < CW*OUTD; v += TPB){
    int i = v >> 6; int k = v & 63;
    s3[v] = w3g[(size_t)(wg*CW + i)*OUTD + k];
  }
  for (int i = tid; i < HID; i += TPB){
    b1s[i] = b1g[i]; d1s[i] = 0.f; o1f[i] = 0.f; a1b[1][i] = 0.f;
  }
  if (tid < OUTD){ b3s[tid] = b3g[tid]; d3b[1][tid] = 0.f; p3r[tid] = 0.f; }
  if (tid < CW){
    b2l[tid] = b2g[wg*CW + tid];
    o2l[tid] = 0.f; d2l[tid] = 0.f; a2b[0][tid] = 0.f; a2b[1][tid] = 0.f;
  }
  __syncthreads();

  // ---- publish u for step 0:  u_j = x_0 . W1_init[:,j] ----
  {
    float ua[CW] = {0.f,0.f,0.f,0.f};
    for (int i = tid; i < HID; i += TPB){
      float xv = xdat[i];
      #pragma unroll
      for (int j = 0; j < CW; j++) ua[j] += xv * s1[j*HID + i];
    }
    #pragma unroll
    for (int j = 0; j < CW; j++){
      float v = wredf(ua[j]);
      if ((tid & 63) == 0) ascr[(tid >> 6)*CW + j] = v;
    }
    __syncthreads();
    if (tid < CW){
      float s = 0.f;
      for (int w = 0; w < 8; w++) s += ascr[w*CW + tid];
      dstore(&U[wg*CW + tid], s);
    }
  }
  int ep = 1;
  gsync(arrive, release, ep++, wg);

  for (int t = 0; t <= NSTEP; t++){
    const int p = t & 1, qq = p ^ 1;
    float* a1c = a1b[p];  float* a1p = a1b[qq];
    float* a2c = a2b[p];  float* a2p = a2b[qq];
    float* d3c = d3b[p];  float* d3p = d3b[qq];

    // ================= Phase A =================
    // stage 1: gather previous-step reductions
    if (tid < 128){
      int s = tid >> 4, b = tid & 15;
      ascr[128 + tid] = dload(&AC[(qq*16 + b)*8 + s]);
    }
    const int i0 = tid, i1 = tid + TPB;
    float u0 = dload(&U[i0]),  u1 = dload(&U[i1]);
    float r0 = dload(&O1R[i0]), r1 = dload(&O1R[i1]);
    float a1p0 = a1p[i0], a1p1 = a1p[i1];
    float of0 = r0 * a1p0 * (1.f - a1p0);
    float of1 = r1 * a1p1 * (1.f - a1p1);
    o1f[i0] = of0; o1f[i1] = of1;
    __syncthreads();

    // stage 2: redundant scalar reductions (identical in every WG)
    {
      float v0 = d1s[i0]*of0 + d1s[i1]*of1;                    // d1 . o1
      float v1 = of0*of0 + of1*of1;                            // |o1|^2
      float Ba = b1s[i0] - LR*of0, Bb = b1s[i1] - LR*of1;
      float v2 = Ba*Ba + Bb*Bb;                                // |b1 - lr o1|^2
      float v3 = a1p0*a1p0 + a1p1*a1p1;                        // |a1_{t-1}|^2
      float v4 = 0.f, v5 = 0.f, v6 = 0.f;
      if (tid < OUTD){
        float d3v = d3p[tid];
        v4 = d3v*d3v;                                          // |d3|^2
        float B3 = b3s[tid] - LR*d3v; v5 = B3*B3;              // |b3 - lr d3|^2
        v6 = d3v * p3r[tid];                                   // d3 . (a2.W3)
      }
      v0 = wredf(v0); v1 = wredf(v1); v2 = wredf(v2); v3 = wredf(v3);
      v4 = wredf(v4); v5 = wredf(v5); v6 = wredf(v6);
      int wid = tid >> 6;
      if ((tid & 63) == 0){
        ascr[wid*8+0]=v0; ascr[wid*8+1]=v1; ascr[wid*8+2]=v2; ascr[wid*8+3]=v3;
        ascr[wid*8+4]=v4; ascr[wid*8+5]=v5; ascr[wid*8+6]=v6;
      }
    }
    __syncthreads();
    float dd=0,so=0,sb=0,sa1=0,sd3=0,sb3=0,dp3=0;
    for (int w = 0; w < 8; w++){
      dd+=ascr[w*8+0]; so+=ascr[w*8+1]; sb+=ascr[w*8+2]; sa1+=ascr[w*8+3];
      sd3+=ascr[w*8+4]; sb3+=ascr[w*8+5]; dp3+=ascr[w*8+6];
    }
    float m1p=0,m2p=0,m3p=0,dq=0,soq=0,sB2=0,sa2=0;
    for (int b = 0; b < 16; b++){
      m1p+=ascr[128+0*16+b]; m2p+=ascr[128+1*16+b]; m3p+=ascr[128+2*16+b];
      dq +=ascr[128+3*16+b]; soq+=ascr[128+4*16+b]; sB2+=ascr[128+5*16+b];
      sa2+=ascr[128+6*16+b];
    }
    float nxp = NX[t > 0 ? t - 1 : 0];
    float sdt = SD[t < NSTEP ? t : 0];
    float n1  = fmaxf(sqrtf(fmaxf(m1p - 2.f*LR*dd  + LR*LR*nxp*so,  0.f)), EPSN);
    float nb1 = fmaxf(sqrtf(sb),  EPSN);
    float n2  = fmaxf(sqrtf(fmaxf(m2p - 2.f*LR*dq  + LR*LR*sa1*soq, 0.f)), EPSN);
    float nb2 = fmaxf(sqrtf(sB2), EPSN);
    float n3  = fmaxf(sqrtf(fmaxf(m3p - 2.f*LR*dp3 + LR*LR*sa2*sd3, 0.f)), EPSN);
    float nb3 = fmaxf(sqrtf(sb3), EPSN);

    // stage 3: redundant b1 update, d1_t, a1_t
    {
      float B0 = (b1s[i0] - LR*of0)/nb1; b1s[i0] = B0;
      float B1 = (b1s[i1] - LR*of1)/nb1; b1s[i1] = B1;
      float dn0 = (u0 - LR*of0*sdt)/n1;  d1s[i0] = dn0;
      float dn1 = (u1 - LR*of1*sdt)/n1;  d1s[i1] = dn1;
      a1c[i0] = sigf(dn0 + B0);
      a1c[i1] = sigf(dn1 + B1);
    }
    __syncthreads();

    // stage 4: fused W2 update (from step t-1 grads) + forward matvec d2 = a1_t . W2_t
    {
      int j = tid >> 7, l = tid & 127;
      float coef = LR * o2l[j];
      float acc = 0.f, ms = 0.f;
      #pragma unroll
      for (int e = 0; e < 8; e++){
        int i = l + (e << 7);
        float w = s2[j*HID + i];
        w = (w - coef*a1p[i]) / n2;
        s2[j*HID + i] = w;
        acc += a1c[i]*w;
        ms  += w*w;
      }
      acc = wredf(acc); ms = wredf(ms);
      int wid = tid >> 6;
      if ((tid & 63) == 0){ ascr[wid] = acc; ascr[8 + wid] = ms; }
    }
    __syncthreads();
    if (tid < CW){
      float d2 = ascr[2*tid] + ascr[2*tid + 1];
      d2l[tid] = d2;
      float b2n = (b2l[tid] - LR*o2l[tid]) / nb2;
      b2l[tid] = b2n;
      a2c[tid] = sigf(d2 + b2n);
    }
    __syncthreads();
    if (tid == 0){
      float m2 = 0.f; for (int w = 0; w < 8; w++) m2 += ascr[8 + w];
      unsafeAtomicAdd(&AC[(p*16 + bank)*8 + 1], m2);
      float s = 0.f;
      for (int j = 0; j < CW; j++){ float a = a2c[j]; s += a*a; }
      unsafeAtomicAdd(&AC[(p*16 + bank)*8 + 6], s);
    }

    // stage 5: fused W3 update + forward partials; redundant b3 update
    if (tid < OUTD){
      int k = tid;
      float d3k = d3p[k];
      float contrib = 0.f, m3s = 0.f;
      #pragma unroll
      for (int i = 0; i < CW; i++){
        float w = s3[i*OUTD + k];
        w = (w - LR*a2p[i]*d3k) / n3;
        s3[i*OUTD + k] = w;
        contrib += a2c[i]*w;
        m3s += w*w;
      }
      unsafeAtomicAdd(&P3[(p*16 + bank)*OUTD + k], contrib);
      m3s = wredf(m3s);
      if (k == 0) unsafeAtomicAdd(&AC[(p*16 + bank)*8 + 2], m3s);
      b3s[k] = (b3s[k] - LR*d3k) / nb3;
    }

    // ===== epilogue: at t == NSTEP the phase-A passes applied the final updates =====
    if (t == NSTEP){
      __syncthreads();
      const float* xl = xdat + (size_t)(NSTEP - 1)*INDIM;
      for (int idx = tid; idx < HID; idx += TPB){
        float xv = xl[idx];
        #pragma unroll
        for (int j = 0; j < CW; j++){
          float w1v = (s1[j*HID + idx] - LR*o1f[wg*CW + j]*xv) / n1;
          out[(size_t)idx*HID + wg*CW + j] = w1v;
          out[(size_t)HID*HID + (size_t)idx*HID + wg*CW + j] = s2[j*HID + idx];
        }
      }
      if (tid < OUTD){
        #pragma unroll
        for (int i = 0; i < CW; i++)
          out[(size_t)2*HID*HID + (size_t)(wg*CW + i)*OUTD + tid] = s3[i*OUTD + tid];
      }
      break;
    }

    gsync(arrive, release, ep++, wg);   // syncP: a3 partials ready

    // ================= Phase B =================
    if (tid < OUTD){
      float s = 0.f;
      for (int b = 0; b < 16; b++) s += dload(&P3[(p*16 + b)*OUTD + tid]);
      p3r[tid] = s;
      float a3 = sigf(s + b3s[tid]);
      float e3 = expf(-a3);
      float es = wredf(e3);
      float net = e3 / es;
      float tv = tgt[(size_t)t*OUTD + tid];
      d3c[tid] = (tv - net) * a3 * (1.f - a3);
    }
    __syncthreads();
    if (tid < CW*OUTD){
      int i = tid >> 6, k = tid & 63;
      float v = s3[i*OUTD + k] * d3c[k];
      v = wredf(v);
      if (k == 0){ float a2v = a2c[i]; o2l[i] = v * a2v * (1.f - a2v); }
    }
    __syncthreads();
    if (tid == 0){
      float dd2 = 0.f, so2 = 0.f, sB2n = 0.f;
      for (int j = 0; j < CW; j++){
        float ov = o2l[j];
        dd2 += d2l[j]*ov; so2 += ov*ov;
        float B = b2l[j] - LR*ov; sB2n += B*B;
      }
      unsafeAtomicAdd(&AC[(p*16 + bank)*8 + 3], dd2);
      unsafeAtomicAdd(&AC[(p*16 + bank)*8 + 4], so2);
      unsafeAtomicAdd(&AC[(p*16 + bank)*8 + 5], sB2n);
    }
    // w2 backward: o1 partials over owned columns
    {
      float q0 = s2[0*HID+i0]*o2l[0] + s2[1*HID+i0]*o2l[1]
               + s2[2*HID+i0]*o2l[2] + s2[3*HID+i0]*o2l[3];
      float q1 = s2[0*HID+i1]*o2l[0] + s2[1*HID+i1]*o2l[1]
               + s2[2*HID+i1]*o2l[2] + s2[3*HID+i1]*o2l[3];
      dstore(&QP[(size_t)wg*HID + i0], q0);
      dstore(&QP[(size_t)wg*HID + i1], q1);
    }
    // fused W1 update (grads of step t-1) + u for step t+1
    {
      const float* xp_ = xdat + (size_t)(t > 0 ? t - 1 : 0)*INDIM;
      const float* xn_ = xdat + (size_t)(t + 1 < NSTEP ? t + 1 : NSTEP - 1)*INDIM;
      float cj[CW];
      #pragma unroll
      for (int j = 0; j < CW; j++) cj[j] = LR * o1f[wg*CW + j];
      float ua[CW] = {0.f,0.f,0.f,0.f};
      float m1s = 0.f;
      #pragma unroll
      for (int pass = 0; pass < 2; pass++){
        int idx = tid + pass*TPB;
        float xpv = xp_[idx], xnv = xn_[idx];
        #pragma unroll
        for (int j = 0; j < CW; j++){
          float w = s1[j*HID + idx];
          w = (w - cj[j]*xpv) / n1;
          s1[j*HID + idx] = w;
          ua[j] += xnv*w;
          m1s += w*w;
        }
      }
      #pragma unroll
      for (int j = 0; j < CW; j++){
        float v = wredf(ua[j]);
        if ((tid & 63) == 0) ascr[(tid >> 6)*CW + j] = v;
      }
      m1s = wredf(m1s);
      if ((tid & 63) == 0) ascr[32 + (tid >> 6)] = m1s;
    }
    __syncthreads();
    if (tid < CW){
      float s = 0.f;
      for (int w = 0; w < 8; w++) s += ascr[w*CW + tid];
      dstore(&U[wg*CW + tid], s);
    }
    if (tid == 0){
      float m1 = 0.f; for (int w = 0; w < 8; w++) m1 += ascr[32 + w];
      unsafeAtomicAdd(&AC[(p*16 + bank)*8 + 0], m1);
    }
    gsync(arrive, release, ep++, wg);   // syncQ: o1 partials published

    // ================= Phase C: reduce o1, zero next-parity accumulators ========
    {
      int c = tid >> 7, l = tid & 127;
      int col = wg*CW + c;
      float s = dload(&QP[(size_t)l*HID + col]) + dload(&QP[(size_t)(l + 128)*HID + col]);
      s = wredf(s);
      int wid = tid >> 6;
      if ((tid & 63) == 0) ascr[wid] = s;
    }
    __syncthreads();
    if (tid < CW) dstore(&O1R[wg*CW + tid], ascr[2*tid] + ascr[2*tid + 1]);
    if (wg < 16){
      if (tid < OUTD) dstore(&P3[(qq*16 + wg)*OUTD + tid], 0.f);
      if (tid < 8)    dstore(&AC[(qq*16 + wg)*8 + tid], 0.f);
    }
    gsync(arrive, release, ep++, wg);   // syncU: o1 ready
  }
}

extern "C" void kernel_launch(void* const* d_in, const int* in_sizes, int n_in,
                              void* d_out, int out_size, void* d_ws, size_t ws_size,
                              hipStream_t stream){
  const float* x  = (const float*)d_in[0];
  const float* tg = (const float*)d_in[1];
  const float* w1 = (const float*)d_in[2];
  const float* b1 = (const float*)d_in[3];
  const float* w2 = (const float*)d_in[4];
  const float* b2 = (const float*)d_in[5];
  const float* w3 = (const float*)d_in[6];
  const float* b3 = (const float*)d_in[7];
  float* out = (float*)d_out;
  float* wsf = (float*)d_ws;
  hipLaunchKernelGGL(bp_init,  dim3(NSTEP), dim3(64),  0, stream, x, wsf);
  hipLaunchKernelGGL(bp_train, dim3(NWG),   dim3(TPB), 0, stream,
                     x, tg, w1, b1, w2, b2, w3, b3, out, wsf);
}

// Round 3
// 1648142.188 us; speedup vs baseline: 1.6105x; 1.6105x over previous
//
#include <hip/hip_runtime.h>
#include <math.h>

// ---------------------------------------------------------------------------
// Persistent-kernel trainer for the 16384-step sequential MLP scan.
// All weights live in LDS, partitioned by ownership:
//   WG g owns w1 columns [4g,4g+4), w2 columns [4g,4g+4), w3 rows [4g,4g+4).
// Cross-WG traffic (agent-scope, MALL-coherent): u (x_t·W1_{t-1}), o1 partials,
// a3 partial sums (64), and norm scalar partials. 3 custom grid syncs / step.
// R3: fence-based barrier — RELAXED spin polls, ONE release fence + ONE acquire
// fence per WG per sync (was: acquire per poll iteration -> L2 inv storm).
// ---------------------------------------------------------------------------

#define NSTEP 16384
#define INDIM 1024
#define HID   1024
#define OUTD  64
#define LR    0.01f
#define EPSN  1e-8f

#define NWG   256
#define TPB   512
#define CW    4      // w1/w2 columns (and w3 rows) per WG

// workspace layout (float indices)
#define OFF_ARRIVE   0                         // 256 ints
#define OFF_RELEASE  512                       // 1 int
#define OFF_QPART    1024                      // NWG*HID
#define OFF_U        (OFF_QPART + NWG*HID)     // HID
#define OFF_O1RAW    (OFF_U + HID)             // HID
#define OFF_P3       (OFF_O1RAW + HID)         // 2*16*64
#define OFF_ACC      (OFF_P3 + 2*16*64)        // 2*16*8
#define OFF_SDOT     (OFF_ACC + 2*16*8)        // NSTEP
#define OFF_NORMX    (OFF_SDOT + NSTEP)        // NSTEP

// ACC scalar slots: 0 m1, 1 m2, 2 m3, 3 dot_d2o2, 4 sum_o2sq, 5 sum_B2sq, 6 sum_a2sq

__device__ __forceinline__ float dload(const float* p){
  return __hip_atomic_load(p, __ATOMIC_RELAXED, __HIP_MEMORY_SCOPE_AGENT);
}
__device__ __forceinline__ void dstore(float* p, float v){
  __hip_atomic_store(p, v, __ATOMIC_RELAXED, __HIP_MEMORY_SCOPE_AGENT);
}
__device__ __forceinline__ int rload(const int* p){
  return __hip_atomic_load(p, __ATOMIC_RELAXED, __HIP_MEMORY_SCOPE_AGENT);
}
__device__ __forceinline__ void rstore(int* p, int v){
  __hip_atomic_store(p, v, __ATOMIC_RELAXED, __HIP_MEMORY_SCOPE_AGENT);
}
__device__ __forceinline__ float wredf(float v){
  #pragma unroll
  for (int m = 32; m; m >>= 1) v += __shfl_xor(v, m, 64);
  return v;
}
__device__ __forceinline__ float sigf(float z){ return 1.f/(1.f+expf(-z)); }

__device__ void gsync(int* arrive, int* release, int e, int wg){
  __builtin_amdgcn_fence(__ATOMIC_RELEASE, "agent");   // one wbl2: publish data
  __syncthreads();
  if (threadIdx.x == 0) rstore(&arrive[wg], e);
  if (wg == 0){
    if (threadIdx.x < NWG){
      while (rload(&arrive[threadIdx.x]) < e)
        __builtin_amdgcn_s_sleep(1);
    }
    __syncthreads();
    if (threadIdx.x == 0){
      __builtin_amdgcn_fence(__ATOMIC_SEQ_CST, "agent"); // transitivity
      rstore(release, e);
    }
  }
  if (threadIdx.x == 0){
    while (rload(release) < e)
      __builtin_amdgcn_s_sleep(1);
  }
  __syncthreads();
  __builtin_amdgcn_fence(__ATOMIC_ACQUIRE, "agent");   // one inv: see remote data
}

// ---------------------------------------------------------------------------
// init kernel: precompute sdot[t] = x_t . x_{t-1}, normx[t] = |x_t|^2 ;
// block 0 additionally zeroes flags/accumulators and seeds t=0 scalars.
// ---------------------------------------------------------------------------
__global__ __launch_bounds__(64) void bp_init(const float* __restrict__ x, float* wsf){
  const int t = blockIdx.x, tid = threadIdx.x;
  const float* xt = x + (size_t)t * INDIM;
  const float* xp = x + (size_t)(t > 0 ? t - 1 : 0) * INDIM;
  float sp = 0.f, nx = 0.f;
  #pragma unroll
  for (int e = 0; e < INDIM/64; e++){
    int i = tid + 64*e; float a = xt[i];
    nx += a*a; sp += a*xp[i];
  }
  sp = wredf(sp); nx = wredf(nx);
  if (tid == 0){ wsf[OFF_SDOT + t] = (t > 0) ? sp : 0.f; wsf[OFF_NORMX + t] = nx; }
  if (blockIdx.x == 0){
    int* wsi = (int*)wsf;
    for (int i = tid; i < 256; i += 64) wsi[OFF_ARRIVE + i] = 0;
    if (tid == 0) wsi[OFF_RELEASE] = 0;
    for (int i = tid; i < HID;      i += 64) wsf[OFF_O1RAW + i] = 0.f;
    for (int i = tid; i < 2*16*64;  i += 64) wsf[OFF_P3 + i]    = 0.f;
    for (int i = tid; i < 2*16*8;   i += 64) wsf[OFF_ACC + i]   = 0.f;
    __syncthreads();
    if (tid == 0){
      float* acc1 = wsf + OFF_ACC + 16*8;   // parity 1, bank 0
      acc1[0] = 1.f; acc1[1] = 1.f; acc1[2] = 1.f; acc1[5] = 1.f; // m1,m2,m3,sumB2sq "prev"
    }
  }
}

// ---------------------------------------------------------------------------
// persistent training kernel
// ---------------------------------------------------------------------------
__global__ __launch_bounds__(TPB) void bp_train(
    const float* __restrict__ xdat, const float* __restrict__ tgt,
    const float* __restrict__ w1g, const float* __restrict__ b1g,
    const float* __restrict__ w2g, const float* __restrict__ b2g,
    const float* __restrict__ w3g, const float* __restrict__ b3g,
    float* __restrict__ out, float* wsf)
{
  __shared__ float s1[CW*HID];      // w1 columns (col-major per column)
  __shared__ float s2[CW*HID];      // w2 columns
  __shared__ float s3[CW*OUTD];     // w3 rows
  __shared__ float a1b[2][HID];     // a1 ping-pong (redundant, all WGs identical)
  __shared__ float d1s[HID];        // d1 (pre-activation of layer 1), redundant
  __shared__ float b1s[HID];        // b1 replica, redundant
  __shared__ float o1f[HID];        // o1 of previous step, redundant
  __shared__ float d3b[2][OUTD];    // d3 ping-pong, redundant
  __shared__ float p3r[OUTD];       // raw a2.W3 dot of previous step, redundant
  __shared__ float b3s[OUTD];       // b3 replica, redundant
  __shared__ float o2l[CW], d2l[CW], b2l[CW];
  __shared__ float a2b[2][CW];
  __shared__ float ascr[256];

  const int tid = threadIdx.x;
  const int wg  = blockIdx.x;
  int*   arrive  = (int*)wsf + OFF_ARRIVE;
  int*   release = (int*)wsf + OFF_RELEASE;
  float* QP  = wsf + OFF_QPART;
  float* U   = wsf + OFF_U;
  float* O1R = wsf + OFF_O1RAW;
  float* P3  = wsf + OFF_P3;
  float* AC  = wsf + OFF_ACC;
  float* SD  = wsf + OFF_SDOT;
  float* NX  = wsf + OFF_NORMX;
  const int bank = wg & 15;

  // ---- load owned slices + replicas, zero state ----
  for (int v = tid; v < CW*HID; v += TPB){
    int j = v & (CW-1); int i = v >> 2;
    s1[j*HID + i] = w1g[(size_t)i*HID + wg*CW + j];
    s2[j*HID + i] = w2g[(size_t)i*HID + wg*CW + j];
  }
  for (int v = tid; v < CW*OUTD; v += TPB){
    int i = v >> 6; int k = v & 63;
    s3[v] = w3g[(size_t)(wg*CW + i)*OUTD + k];
  }
  for (int i = tid; i < HID; i += TPB){
    b1s[i] = b1g[i]; d1s[i] = 0.f; o1f[i] = 0.f; a1b[1][i] = 0.f;
  }
  if (tid < OUTD){ b3s[tid] = b3g[tid]; d3b[1][tid] = 0.f; p3r[tid] = 0.f; }
  if (tid < CW){
    b2l[tid] = b2g[wg*CW + tid];
    o2l[tid] = 0.f; d2l[tid] = 0.f; a2b[0][tid] = 0.f; a2b[1][tid] = 0.f;
  }
  __syncthreads();

  // ---- publish u for step 0:  u_j = x_0 . W1_init[:,j] ----
  {
    float ua[CW] = {0.f,0.f,0.f,0.f};
    for (int i = tid; i < HID; i += TPB){
      float xv = xdat[i];
      #pragma unroll
      for (int j = 0; j < CW; j++) ua[j] += xv * s1[j*HID + i];
    }
    #pragma unroll
    for (int j = 0; j < CW; j++){
      float v = wredf(ua[j]);
      if ((tid & 63) == 0) ascr[(tid >> 6)*CW + j] = v;
    }
    __syncthreads();
    if (tid < CW){
      float s = 0.f;
      for (int w = 0; w < 8; w++) s += ascr[w*CW + tid];
      dstore(&U[wg*CW + tid], s);
    }
  }
  int ep = 1;
  gsync(arrive, release, ep++, wg);

  for (int t = 0; t <= NSTEP; t++){
    const int p = t & 1, qq = p ^ 1;
    float* a1c = a1b[p];  float* a1p = a1b[qq];
    float* a2c = a2b[p];  float* a2p = a2b[qq];
    float* d3c = d3b[p];  float* d3p = d3b[qq];

    // ================= Phase A =================
    // stage 1: gather previous-step reductions
    if (tid < 128){
      int s = tid >> 4, b = tid & 15;
      ascr[128 + tid] = dload(&AC[(qq*16 + b)*8 + s]);
    }
    const int i0 = tid, i1 = tid + TPB;
    float u0 = dload(&U[i0]),  u1 = dload(&U[i1]);
    float r0 = dload(&O1R[i0]), r1 = dload(&O1R[i1]);
    float a1p0 = a1p[i0], a1p1 = a1p[i1];
    float of0 = r0 * a1p0 * (1.f - a1p0);
    float of1 = r1 * a1p1 * (1.f - a1p1);
    o1f[i0] = of0; o1f[i1] = of1;
    __syncthreads();

    // stage 2: redundant scalar reductions (identical in every WG)
    {
      float v0 = d1s[i0]*of0 + d1s[i1]*of1;                    // d1 . o1
      float v1 = of0*of0 + of1*of1;                            // |o1|^2
      float Ba = b1s[i0] - LR*of0, Bb = b1s[i1] - LR*of1;
      float v2 = Ba*Ba + Bb*Bb;                                // |b1 - lr o1|^2
      float v3 = a1p0*a1p0 + a1p1*a1p1;                        // |a1_{t-1}|^2
      float v4 = 0.f, v5 = 0.f, v6 = 0.f;
      if (tid < OUTD){
        float d3v = d3p[tid];
        v4 = d3v*d3v;                                          // |d3|^2
        float B3 = b3s[tid] - LR*d3v; v5 = B3*B3;              // |b3 - lr d3|^2
        v6 = d3v * p3r[tid];                                   // d3 . (a2.W3)
      }
      v0 = wredf(v0); v1 = wredf(v1); v2 = wredf(v2); v3 = wredf(v3);
      v4 = wredf(v4); v5 = wredf(v5); v6 = wredf(v6);
      int wid = tid >> 6;
      if ((tid & 63) == 0){
        ascr[wid*8+0]=v0; ascr[wid*8+1]=v1; ascr[wid*8+2]=v2; ascr[wid*8+3]=v3;
        ascr[wid*8+4]=v4; ascr[wid*8+5]=v5; ascr[wid*8+6]=v6;
      }
    }
    __syncthreads();
    float dd=0,so=0,sb=0,sa1=0,sd3=0,sb3=0,dp3=0;
    for (int w = 0; w < 8; w++){
      dd+=ascr[w*8+0]; so+=ascr[w*8+1]; sb+=ascr[w*8+2]; sa1+=ascr[w*8+3];
      sd3+=ascr[w*8+4]; sb3+=ascr[w*8+5]; dp3+=ascr[w*8+6];
    }
    float m1p=0,m2p=0,m3p=0,dq=0,soq=0,sB2=0,sa2=0;
    for (int b = 0; b < 16; b++){
      m1p+=ascr[128+0*16+b]; m2p+=ascr[128+1*16+b]; m3p+=ascr[128+2*16+b];
      dq +=ascr[128+3*16+b]; soq+=ascr[128+4*16+b]; sB2+=ascr[128+5*16+b];
      sa2+=ascr[128+6*16+b];
    }
    float nxp = NX[t > 0 ? t - 1 : 0];
    float sdt = SD[t < NSTEP ? t : 0];
    float n1  = fmaxf(sqrtf(fmaxf(m1p - 2.f*LR*dd  + LR*LR*nxp*so,  0.f)), EPSN);
    float nb1 = fmaxf(sqrtf(sb),  EPSN);
    float n2  = fmaxf(sqrtf(fmaxf(m2p - 2.f*LR*dq  + LR*LR*sa1*soq, 0.f)), EPSN);
    float nb2 = fmaxf(sqrtf(sB2), EPSN);
    float n3  = fmaxf(sqrtf(fmaxf(m3p - 2.f*LR*dp3 + LR*LR*sa2*sd3, 0.f)), EPSN);
    float nb3 = fmaxf(sqrtf(sb3), EPSN);

    // stage 3: redundant b1 update, d1_t, a1_t
    {
      float B0 = (b1s[i0] - LR*of0)/nb1; b1s[i0] = B0;
      float B1 = (b1s[i1] - LR*of1)/nb1; b1s[i1] = B1;
      float dn0 = (u0 - LR*of0*sdt)/n1;  d1s[i0] = dn0;
      float dn1 = (u1 - LR*of1*sdt)/n1;  d1s[i1] = dn1;
      a1c[i0] = sigf(dn0 + B0);
      a1c[i1] = sigf(dn1 + B1);
    }
    __syncthreads();

    // stage 4: fused W2 update (from step t-1 grads) + forward matvec d2 = a1_t . W2_t
    {
      int j = tid >> 7, l = tid & 127;
      float coef = LR * o2l[j];
      float acc = 0.f, ms = 0.f;
      #pragma unroll
      for (int e = 0; e < 8; e++){
        int i = l + (e << 7);
        float w = s2[j*HID + i];
        w = (w - coef*a1p[i]) / n2;
        s2[j*HID + i] = w;
        acc += a1c[i]*w;
        ms  += w*w;
      }
      acc = wredf(acc); ms = wredf(ms);
      int wid = tid >> 6;
      if ((tid & 63) == 0){ ascr[wid] = acc; ascr[8 + wid] = ms; }
    }
    __syncthreads();
    if (tid < CW){
      float d2 = ascr[2*tid] + ascr[2*tid + 1];
      d2l[tid] = d2;
      float b2n = (b2l[tid] - LR*o2l[tid]) / nb2;
      b2l[tid] = b2n;
      a2c[tid] = sigf(d2 + b2n);
    }
    __syncthreads();
    if (tid == 0){
      float m2 = 0.f; for (int w = 0; w < 8; w++) m2 += ascr[8 + w];
      unsafeAtomicAdd(&AC[(p*16 + bank)*8 + 1], m2);
      float s = 0.f;
      for (int j = 0; j < CW; j++){ float a = a2c[j]; s += a*a; }
      unsafeAtomicAdd(&AC[(p*16 + bank)*8 + 6], s);
    }

    // stage 5: fused W3 update + forward partials; redundant b3 update
    if (tid < OUTD){
      int k = tid;
      float d3k = d3p[k];
      float contrib = 0.f, m3s = 0.f;
      #pragma unroll
      for (int i = 0; i < CW; i++){
        float w = s3[i*OUTD + k];
        w = (w - LR*a2p[i]*d3k) / n3;
        s3[i*OUTD + k] = w;
        contrib += a2c[i]*w;
        m3s += w*w;
      }
      unsafeAtomicAdd(&P3[(p*16 + bank)*OUTD + k], contrib);
      m3s = wredf(m3s);
      if (k == 0) unsafeAtomicAdd(&AC[(p*16 + bank)*8 + 2], m3s);
      b3s[k] = (b3s[k] - LR*d3k) / nb3;
    }

    // ===== epilogue: at t == NSTEP the phase-A passes applied the final updates =====
    if (t == NSTEP){
      __syncthreads();
      const float* xl = xdat + (size_t)(NSTEP - 1)*INDIM;
      for (int idx = tid; idx < HID; idx += TPB){
        float xv = xl[idx];
        #pragma unroll
        for (int j = 0; j < CW; j++){
          float w1v = (s1[j*HID + idx] - LR*o1f[wg*CW + j]*xv) / n1;
          out[(size_t)idx*HID + wg*CW + j] = w1v;
          out[(size_t)HID*HID + (size_t)idx*HID + wg*CW + j] = s2[j*HID + idx];
        }
      }
      if (tid < OUTD){
        #pragma unroll
        for (int i = 0; i < CW; i++)
          out[(size_t)2*HID*HID + (size_t)(wg*CW + i)*OUTD + tid] = s3[i*OUTD + tid];
      }
      break;
    }

    gsync(arrive, release, ep++, wg);   // syncP: a3 partials ready

    // ================= Phase B =================
    if (tid < OUTD){
      float s = 0.f;
      for (int b = 0; b < 16; b++) s += dload(&P3[(p*16 + b)*OUTD + tid]);
      p3r[tid] = s;
      float a3 = sigf(s + b3s[tid]);
      float e3 = expf(-a3);
      float es = wredf(e3);
      float net = e3 / es;
      float tv = tgt[(size_t)t*OUTD + tid];
      d3c[tid] = (tv - net) * a3 * (1.f - a3);
    }
    __syncthreads();
    if (tid < CW*OUTD){
      int i = tid >> 6, k = tid & 63;
      float v = s3[i*OUTD + k] * d3c[k];
      v = wredf(v);
      if (k == 0){ float a2v = a2c[i]; o2l[i] = v * a2v * (1.f - a2v); }
    }
    __syncthreads();
    if (tid == 0){
      float dd2 = 0.f, so2 = 0.f, sB2n = 0.f;
      for (int j = 0; j < CW; j++){
        float ov = o2l[j];
        dd2 += d2l[j]*ov; so2 += ov*ov;
        float B = b2l[j] - LR*ov; sB2n += B*B;
      }
      unsafeAtomicAdd(&AC[(p*16 + bank)*8 + 3], dd2);
      unsafeAtomicAdd(&AC[(p*16 + bank)*8 + 4], so2);
      unsafeAtomicAdd(&AC[(p*16 + bank)*8 + 5], sB2n);
    }
    // w2 backward: o1 partials over owned columns
    {
      float q0 = s2[0*HID+i0]*o2l[0] + s2[1*HID+i0]*o2l[1]
               + s2[2*HID+i0]*o2l[2] + s2[3*HID+i0]*o2l[3];
      float q1 = s2[0*HID+i1]*o2l[0] + s2[1*HID+i1]*o2l[1]
               + s2[2*HID+i1]*o2l[2] + s2[3*HID+i1]*o2l[3];
      dstore(&QP[(size_t)wg*HID + i0], q0);
      dstore(&QP[(size_t)wg*HID + i1], q1);
    }
    // fused W1 update (grads of step t-1) + u for step t+1
    {
      const float* xp_ = xdat + (size_t)(t > 0 ? t - 1 : 0)*INDIM;
      const float* xn_ = xdat + (size_t)(t + 1 < NSTEP ? t + 1 : NSTEP - 1)*INDIM;
      float cj[CW];
      #pragma unroll
      for (int j = 0; j < CW; j++) cj[j] = LR * o1f[wg*CW + j];
      float ua[CW] = {0.f,0.f,0.f,0.f};
      float m1s = 0.f;
      #pragma unroll
      for (int pass = 0; pass < 2; pass++){
        int idx = tid + pass*TPB;
        float xpv = xp_[idx], xnv = xn_[idx];
        #pragma unroll
        for (int j = 0; j < CW; j++){
          float w = s1[j*HID + idx];
          w = (w - cj[j]*xpv) / n1;
          s1[j*HID + idx] = w;
          ua[j] += xnv*w;
          m1s += w*w;
        }
      }
      #pragma unroll
      for (int j = 0; j < CW; j++){
        float v = wredf(ua[j]);
        if ((tid & 63) == 0) ascr[(tid >> 6)*CW + j] = v;
      }
      m1s = wredf(m1s);
      if ((tid & 63) == 0) ascr[32 + (tid >> 6)] = m1s;
    }
    __syncthreads();
    if (tid < CW){
      float s = 0.f;
      for (int w = 0; w < 8; w++) s += ascr[w*CW + tid];
      dstore(&U[wg*CW + tid], s);
    }
    if (tid == 0){
      float m1 = 0.f; for (int w = 0; w < 8; w++) m1 += ascr[32 + w];
      unsafeAtomicAdd(&AC[(p*16 + bank)*8 + 0], m1);
    }
    gsync(arrive, release, ep++, wg);   // syncQ: o1 partials published

    // ================= Phase C: reduce o1, zero next-parity accumulators ========
    {
      int c = tid >> 7, l = tid & 127;
      int col = wg*CW + c;
      float s = dload(&QP[(size_t)l*HID + col]) + dload(&QP[(size_t)(l + 128)*HID + col]);
      s = wredf(s);
      int wid = tid >> 6;
      if ((tid & 63) == 0) ascr[wid] = s;
    }
    __syncthreads();
    if (tid < CW) dstore(&O1R[wg*CW + tid], ascr[2*tid] + ascr[2*tid + 1]);
    if (wg < 16){
      if (tid < OUTD) dstore(&P3[(qq*16 + wg)*OUTD + tid], 0.f);
      if (tid < 8)    dstore(&AC[(qq*16 + wg)*8 + tid], 0.f);
    }
    gsync(arrive, release, ep++, wg);   // syncU: o1 ready
  }
}

extern "C" void kernel_launch(void* const* d_in, const int* in_sizes, int n_in,
                              void* d_out, int out_size, void* d_ws, size_t ws_size,
                              hipStream_t stream){
  const float* x  = (const float*)d_in[0];
  const float* tg = (const float*)d_in[1];
  const float* w1 = (const float*)d_in[2];
  const float* b1 = (const float*)d_in[3];
  const float* w2 = (const float*)d_in[4];
  const float* b2 = (const float*)d_in[5];
  const float* w3 = (const float*)d_in[6];
  const float* b3 = (const float*)d_in[7];
  float* out = (float*)d_out;
  float* wsf = (float*)d_ws;
  hipLaunchKernelGGL(bp_init,  dim3(NSTEP), dim3(64),  0, stream, x, wsf);
  hipLaunchKernelGGL(bp_train, dim3(NWG),   dim3(TPB), 0, stream,
                     x, tg, w1, b1, w2, b2, w3, b3, out, wsf);
}

// Round 4
// 311305.566 us; speedup vs baseline: 8.5267x; 5.2943x over previous
//
#include <hip/hip_runtime.h>
#include <math.h>

// ---------------------------------------------------------------------------
// Persistent-kernel trainer for the 16384-step sequential MLP scan.
// All weights live in LDS, partitioned by ownership:
//   WG g owns w1 columns [4g,4g+4), w2 columns [4g,4g+4), w3 rows [4g,4g+4).
// Cross-WG traffic (agent-scope relaxed atomics = sc1 ops at MALL): u, o1
// partials, a3 partials (64), norm scalar partials. 3 custom grid syncs/step.
// R4: NO cache-maintenance fences. All cross-WG data moves via agent-scope
// atomics (sc1 -> coherent at MALL, bypassing per-XCD L2), so the only
// ordering needed is vmcnt-drain before the arrive-flag store. The R3
// buffer_wbl2/buffer_inv per WG per sync (~33us/sync, serialized at L2)
// protected nothing.
// ---------------------------------------------------------------------------

#define NSTEP 16384
#define INDIM 1024
#define HID   1024
#define OUTD  64
#define LR    0.01f
#define EPSN  1e-8f

#define NWG   256
#define TPB   512
#define CW    4      // w1/w2 columns (and w3 rows) per WG

// workspace layout (float indices)
#define OFF_ARRIVE   0                         // 256 ints
#define OFF_RELEASE  512                       // 1 int
#define OFF_QPART    1024                      // NWG*HID
#define OFF_U        (OFF_QPART + NWG*HID)     // HID
#define OFF_O1RAW    (OFF_U + HID)             // HID
#define OFF_P3       (OFF_O1RAW + HID)         // 2*16*64
#define OFF_ACC      (OFF_P3 + 2*16*64)        // 2*16*8
#define OFF_SDOT     (OFF_ACC + 2*16*8)        // NSTEP
#define OFF_NORMX    (OFF_SDOT + NSTEP)        // NSTEP

// ACC scalar slots: 0 m1, 1 m2, 2 m3, 3 dot_d2o2, 4 sum_o2sq, 5 sum_B2sq, 6 sum_a2sq

__device__ __forceinline__ float dload(const float* p){
  return __hip_atomic_load(p, __ATOMIC_RELAXED, __HIP_MEMORY_SCOPE_AGENT);
}
__device__ __forceinline__ void dstore(float* p, float v){
  __hip_atomic_store(p, v, __ATOMIC_RELAXED, __HIP_MEMORY_SCOPE_AGENT);
}
__device__ __forceinline__ int rload(const int* p){
  return __hip_atomic_load(p, __ATOMIC_RELAXED, __HIP_MEMORY_SCOPE_AGENT);
}
__device__ __forceinline__ void rstore(int* p, int v){
  __hip_atomic_store(p, v, __ATOMIC_RELAXED, __HIP_MEMORY_SCOPE_AGENT);
}
__device__ __forceinline__ float wredf(float v){
  #pragma unroll
  for (int m = 32; m; m >>= 1) v += __shfl_xor(v, m, 64);
  return v;
}
__device__ __forceinline__ float sigf(float z){ return 1.f/(1.f+expf(-z)); }

__device__ void gsync(int* arrive, int* release, int e, int wg){
  // Every wave drains its outstanding sc1 stores (ack'd at MALL), then the
  // block barrier guarantees all waves drained before tid0 sets the flag.
  asm volatile("s_waitcnt vmcnt(0) lgkmcnt(0)" ::: "memory");
  __syncthreads();
  if (threadIdx.x == 0) rstore(&arrive[wg], e);
  if (wg == 0){
    if (threadIdx.x < NWG){
      while (rload(&arrive[threadIdx.x]) < e)
        __builtin_amdgcn_s_sleep(1);
    }
    __syncthreads();
    if (threadIdx.x == 0) rstore(release, e);
  }
  if (threadIdx.x == 0){
    while (rload(release) < e)
      __builtin_amdgcn_s_sleep(1);
  }
  __syncthreads();
  asm volatile("" ::: "memory");   // compiler barrier only; sc1 loads re-fetch from MALL
}

// ---------------------------------------------------------------------------
// init kernel: precompute sdot[t] = x_t . x_{t-1}, normx[t] = |x_t|^2 ;
// block 0 additionally zeroes flags/accumulators and seeds t=0 scalars.
// ---------------------------------------------------------------------------
__global__ __launch_bounds__(64) void bp_init(const float* __restrict__ x, float* wsf){
  const int t = blockIdx.x, tid = threadIdx.x;
  const float* xt = x + (size_t)t * INDIM;
  const float* xp = x + (size_t)(t > 0 ? t - 1 : 0) * INDIM;
  float sp = 0.f, nx = 0.f;
  #pragma unroll
  for (int e = 0; e < INDIM/64; e++){
    int i = tid + 64*e; float a = xt[i];
    nx += a*a; sp += a*xp[i];
  }
  sp = wredf(sp); nx = wredf(nx);
  if (tid == 0){ wsf[OFF_SDOT + t] = (t > 0) ? sp : 0.f; wsf[OFF_NORMX + t] = nx; }
  if (blockIdx.x == 0){
    int* wsi = (int*)wsf;
    for (int i = tid; i < 256; i += 64) wsi[OFF_ARRIVE + i] = 0;
    if (tid == 0) wsi[OFF_RELEASE] = 0;
    for (int i = tid; i < HID;      i += 64) wsf[OFF_O1RAW + i] = 0.f;
    for (int i = tid; i < 2*16*64;  i += 64) wsf[OFF_P3 + i]    = 0.f;
    for (int i = tid; i < 2*16*8;   i += 64) wsf[OFF_ACC + i]   = 0.f;
    __syncthreads();
    if (tid == 0){
      float* acc1 = wsf + OFF_ACC + 16*8;   // parity 1, bank 0
      acc1[0] = 1.f; acc1[1] = 1.f; acc1[2] = 1.f; acc1[5] = 1.f; // m1,m2,m3,sumB2sq "prev"
    }
  }
}

// ---------------------------------------------------------------------------
// persistent training kernel
// ---------------------------------------------------------------------------
__global__ __launch_bounds__(TPB) void bp_train(
    const float* __restrict__ xdat, const float* __restrict__ tgt,
    const float* __restrict__ w1g, const float* __restrict__ b1g,
    const float* __restrict__ w2g, const float* __restrict__ b2g,
    const float* __restrict__ w3g, const float* __restrict__ b3g,
    float* __restrict__ out, float* wsf)
{
  __shared__ float s1[CW*HID];      // w1 columns (col-major per column)
  __shared__ float s2[CW*HID];      // w2 columns
  __shared__ float s3[CW*OUTD];     // w3 rows
  __shared__ float a1b[2][HID];     // a1 ping-pong (redundant, all WGs identical)
  __shared__ float d1s[HID];        // d1 (pre-activation of layer 1), redundant
  __shared__ float b1s[HID];        // b1 replica, redundant
  __shared__ float o1f[HID];        // o1 of previous step, redundant
  __shared__ float d3b[2][OUTD];    // d3 ping-pong, redundant
  __shared__ float p3r[OUTD];       // raw a2.W3 dot of previous step, redundant
  __shared__ float b3s[OUTD];       // b3 replica, redundant
  __shared__ float o2l[CW], d2l[CW], b2l[CW];
  __shared__ float a2b[2][CW];
  __shared__ float ascr[256];

  const int tid = threadIdx.x;
  const int wg  = blockIdx.x;
  int*   arrive  = (int*)wsf + OFF_ARRIVE;
  int*   release = (int*)wsf + OFF_RELEASE;
  float* QP  = wsf + OFF_QPART;
  float* U   = wsf + OFF_U;
  float* O1R = wsf + OFF_O1RAW;
  float* P3  = wsf + OFF_P3;
  float* AC  = wsf + OFF_ACC;
  float* SD  = wsf + OFF_SDOT;
  float* NX  = wsf + OFF_NORMX;
  const int bank = wg & 15;

  // ---- load owned slices + replicas, zero state ----
  for (int v = tid; v < CW*HID; v += TPB){
    int j = v & (CW-1); int i = v >> 2;
    s1[j*HID + i] = w1g[(size_t)i*HID + wg*CW + j];
    s2[j*HID + i] = w2g[(size_t)i*HID + wg*CW + j];
  }
  for (int v = tid; v < CW*OUTD; v += TPB){
    int i = v >> 6; int k = v & 63;
    s3[v] = w3g[(size_t)(wg*CW + i)*OUTD + k];
  }
  for (int i = tid; i < HID; i += TPB){
    b1s[i] = b1g[i]; d1s[i] = 0.f; o1f[i] = 0.f; a1b[1][i] = 0.f;
  }
  if (tid < OUTD){ b3s[tid] = b3g[tid]; d3b[1][tid] = 0.f; p3r[tid] = 0.f; }
  if (tid < CW){
    b2l[tid] = b2g[wg*CW + tid];
    o2l[tid] = 0.f; d2l[tid] = 0.f; a2b[0][tid] = 0.f; a2b[1][tid] = 0.f;
  }
  __syncthreads();

  // ---- publish u for step 0:  u_j = x_0 . W1_init[:,j] ----
  {
    float ua[CW] = {0.f,0.f,0.f,0.f};
    for (int i = tid; i < HID; i += TPB){
      float xv = xdat[i];
      #pragma unroll
      for (int j = 0; j < CW; j++) ua[j] += xv * s1[j*HID + i];
    }
    #pragma unroll
    for (int j = 0; j < CW; j++){
      float v = wredf(ua[j]);
      if ((tid & 63) == 0) ascr[(tid >> 6)*CW + j] = v;
    }
    __syncthreads();
    if (tid < CW){
      float s = 0.f;
      for (int w = 0; w < 8; w++) s += ascr[w*CW + tid];
      dstore(&U[wg*CW + tid], s);
    }
  }
  int ep = 1;
  gsync(arrive, release, ep++, wg);

  for (int t = 0; t <= NSTEP; t++){
    const int p = t & 1, qq = p ^ 1;
    float* a1c = a1b[p];  float* a1p = a1b[qq];
    float* a2c = a2b[p];  float* a2p = a2b[qq];
    float* d3c = d3b[p];  float* d3p = d3b[qq];

    // ================= Phase A =================
    // stage 1: gather previous-step reductions
    if (tid < 128){
      int s = tid >> 4, b = tid & 15;
      ascr[128 + tid] = dload(&AC[(qq*16 + b)*8 + s]);
    }
    const int i0 = tid, i1 = tid + TPB;
    float u0 = dload(&U[i0]),  u1 = dload(&U[i1]);
    float r0 = dload(&O1R[i0]), r1 = dload(&O1R[i1]);
    float a1p0 = a1p[i0], a1p1 = a1p[i1];
    float of0 = r0 * a1p0 * (1.f - a1p0);
    float of1 = r1 * a1p1 * (1.f - a1p1);
    o1f[i0] = of0; o1f[i1] = of1;
    __syncthreads();

    // stage 2: redundant scalar reductions (identical in every WG)
    {
      float v0 = d1s[i0]*of0 + d1s[i1]*of1;                    // d1 . o1
      float v1 = of0*of0 + of1*of1;                            // |o1|^2
      float Ba = b1s[i0] - LR*of0, Bb = b1s[i1] - LR*of1;
      float v2 = Ba*Ba + Bb*Bb;                                // |b1 - lr o1|^2
      float v3 = a1p0*a1p0 + a1p1*a1p1;                        // |a1_{t-1}|^2
      float v4 = 0.f, v5 = 0.f, v6 = 0.f;
      if (tid < OUTD){
        float d3v = d3p[tid];
        v4 = d3v*d3v;                                          // |d3|^2
        float B3 = b3s[tid] - LR*d3v; v5 = B3*B3;              // |b3 - lr d3|^2
        v6 = d3v * p3r[tid];                                   // d3 . (a2.W3)
      }
      v0 = wredf(v0); v1 = wredf(v1); v2 = wredf(v2); v3 = wredf(v3);
      v4 = wredf(v4); v5 = wredf(v5); v6 = wredf(v6);
      int wid = tid >> 6;
      if ((tid & 63) == 0){
        ascr[wid*8+0]=v0; ascr[wid*8+1]=v1; ascr[wid*8+2]=v2; ascr[wid*8+3]=v3;
        ascr[wid*8+4]=v4; ascr[wid*8+5]=v5; ascr[wid*8+6]=v6;
      }
    }
    __syncthreads();
    float dd=0,so=0,sb=0,sa1=0,sd3=0,sb3=0,dp3=0;
    for (int w = 0; w < 8; w++){
      dd+=ascr[w*8+0]; so+=ascr[w*8+1]; sb+=ascr[w*8+2]; sa1+=ascr[w*8+3];
      sd3+=ascr[w*8+4]; sb3+=ascr[w*8+5]; dp3+=ascr[w*8+6];
    }
    float m1p=0,m2p=0,m3p=0,dq=0,soq=0,sB2=0,sa2=0;
    for (int b = 0; b < 16; b++){
      m1p+=ascr[128+0*16+b]; m2p+=ascr[128+1*16+b]; m3p+=ascr[128+2*16+b];
      dq +=ascr[128+3*16+b]; soq+=ascr[128+4*16+b]; sB2+=ascr[128+5*16+b];
      sa2+=ascr[128+6*16+b];
    }
    float nxp = NX[t > 0 ? t - 1 : 0];
    float sdt = SD[t < NSTEP ? t : 0];
    float n1  = fmaxf(sqrtf(fmaxf(m1p - 2.f*LR*dd  + LR*LR*nxp*so,  0.f)), EPSN);
    float nb1 = fmaxf(sqrtf(sb),  EPSN);
    float n2  = fmaxf(sqrtf(fmaxf(m2p - 2.f*LR*dq  + LR*LR*sa1*soq, 0.f)), EPSN);
    float nb2 = fmaxf(sqrtf(sB2), EPSN);
    float n3  = fmaxf(sqrtf(fmaxf(m3p - 2.f*LR*dp3 + LR*LR*sa2*sd3, 0.f)), EPSN);
    float nb3 = fmaxf(sqrtf(sb3), EPSN);

    // stage 3: redundant b1 update, d1_t, a1_t
    {
      float B0 = (b1s[i0] - LR*of0)/nb1; b1s[i0] = B0;
      float B1 = (b1s[i1] - LR*of1)/nb1; b1s[i1] = B1;
      float dn0 = (u0 - LR*of0*sdt)/n1;  d1s[i0] = dn0;
      float dn1 = (u1 - LR*of1*sdt)/n1;  d1s[i1] = dn1;
      a1c[i0] = sigf(dn0 + B0);
      a1c[i1] = sigf(dn1 + B1);
    }
    __syncthreads();

    // stage 4: fused W2 update (from step t-1 grads) + forward matvec d2 = a1_t . W2_t
    {
      int j = tid >> 7, l = tid & 127;
      float coef = LR * o2l[j];
      float acc = 0.f, ms = 0.f;
      #pragma unroll
      for (int e = 0; e < 8; e++){
        int i = l + (e << 7);
        float w = s2[j*HID + i];
        w = (w - coef*a1p[i]) / n2;
        s2[j*HID + i] = w;
        acc += a1c[i]*w;
        ms  += w*w;
      }
      acc = wredf(acc); ms = wredf(ms);
      int wid = tid >> 6;
      if ((tid & 63) == 0){ ascr[wid] = acc; ascr[8 + wid] = ms; }
    }
    __syncthreads();
    if (tid < CW){
      float d2 = ascr[2*tid] + ascr[2*tid + 1];
      d2l[tid] = d2;
      float b2n = (b2l[tid] - LR*o2l[tid]) / nb2;
      b2l[tid] = b2n;
      a2c[tid] = sigf(d2 + b2n);
    }
    __syncthreads();
    if (tid == 0){
      float m2 = 0.f; for (int w = 0; w < 8; w++) m2 += ascr[8 + w];
      unsafeAtomicAdd(&AC[(p*16 + bank)*8 + 1], m2);
      float s = 0.f;
      for (int j = 0; j < CW; j++){ float a = a2c[j]; s += a*a; }
      unsafeAtomicAdd(&AC[(p*16 + bank)*8 + 6], s);
    }

    // stage 5: fused W3 update + forward partials; redundant b3 update
    if (tid < OUTD){
      int k = tid;
      float d3k = d3p[k];
      float contrib = 0.f, m3s = 0.f;
      #pragma unroll
      for (int i = 0; i < CW; i++){
        float w = s3[i*OUTD + k];
        w = (w - LR*a2p[i]*d3k) / n3;
        s3[i*OUTD + k] = w;
        contrib += a2c[i]*w;
        m3s += w*w;
      }
      unsafeAtomicAdd(&P3[(p*16 + bank)*OUTD + k], contrib);
      m3s = wredf(m3s);
      if (k == 0) unsafeAtomicAdd(&AC[(p*16 + bank)*8 + 2], m3s);
      b3s[k] = (b3s[k] - LR*d3k) / nb3;
    }

    // ===== epilogue: at t == NSTEP the phase-A passes applied the final updates =====
    if (t == NSTEP){
      __syncthreads();
      const float* xl = xdat + (size_t)(NSTEP - 1)*INDIM;
      for (int idx = tid; idx < HID; idx += TPB){
        float xv = xl[idx];
        #pragma unroll
        for (int j = 0; j < CW; j++){
          float w1v = (s1[j*HID + idx] - LR*o1f[wg*CW + j]*xv) / n1;
          out[(size_t)idx*HID + wg*CW + j] = w1v;
          out[(size_t)HID*HID + (size_t)idx*HID + wg*CW + j] = s2[j*HID + idx];
        }
      }
      if (tid < OUTD){
        #pragma unroll
        for (int i = 0; i < CW; i++)
          out[(size_t)2*HID*HID + (size_t)(wg*CW + i)*OUTD + tid] = s3[i*OUTD + tid];
      }
      break;
    }

    gsync(arrive, release, ep++, wg);   // syncP: a3 partials ready

    // ================= Phase B =================
    if (tid < OUTD){
      float s = 0.f;
      for (int b = 0; b < 16; b++) s += dload(&P3[(p*16 + b)*OUTD + tid]);
      p3r[tid] = s;
      float a3 = sigf(s + b3s[tid]);
      float e3 = expf(-a3);
      float es = wredf(e3);
      float net = e3 / es;
      float tv = tgt[(size_t)t*OUTD + tid];
      d3c[tid] = (tv - net) * a3 * (1.f - a3);
    }
    __syncthreads();
    if (tid < CW*OUTD){
      int i = tid >> 6, k = tid & 63;
      float v = s3[i*OUTD + k] * d3c[k];
      v = wredf(v);
      if (k == 0){ float a2v = a2c[i]; o2l[i] = v * a2v * (1.f - a2v); }
    }
    __syncthreads();
    if (tid == 0){
      float dd2 = 0.f, so2 = 0.f, sB2n = 0.f;
      for (int j = 0; j < CW; j++){
        float ov = o2l[j];
        dd2 += d2l[j]*ov; so2 += ov*ov;
        float B = b2l[j] - LR*ov; sB2n += B*B;
      }
      unsafeAtomicAdd(&AC[(p*16 + bank)*8 + 3], dd2);
      unsafeAtomicAdd(&AC[(p*16 + bank)*8 + 4], so2);
      unsafeAtomicAdd(&AC[(p*16 + bank)*8 + 5], sB2n);
    }
    // w2 backward: o1 partials over owned columns
    {
      float q0 = s2[0*HID+i0]*o2l[0] + s2[1*HID+i0]*o2l[1]
               + s2[2*HID+i0]*o2l[2] + s2[3*HID+i0]*o2l[3];
      float q1 = s2[0*HID+i1]*o2l[0] + s2[1*HID+i1]*o2l[1]
               + s2[2*HID+i1]*o2l[2] + s2[3*HID+i1]*o2l[3];
      dstore(&QP[(size_t)wg*HID + i0], q0);
      dstore(&QP[(size_t)wg*HID + i1], q1);
    }
    // fused W1 update (grads of step t-1) + u for step t+1
    {
      const float* xp_ = xdat + (size_t)(t > 0 ? t - 1 : 0)*INDIM;
      const float* xn_ = xdat + (size_t)(t + 1 < NSTEP ? t + 1 : NSTEP - 1)*INDIM;
      float cj[CW];
      #pragma unroll
      for (int j = 0; j < CW; j++) cj[j] = LR * o1f[wg*CW + j];
      float ua[CW] = {0.f,0.f,0.f,0.f};
      float m1s = 0.f;
      #pragma unroll
      for (int pass = 0; pass < 2; pass++){
        int idx = tid + pass*TPB;
        float xpv = xp_[idx], xnv = xn_[idx];
        #pragma unroll
        for (int j = 0; j < CW; j++){
          float w = s1[j*HID + idx];
          w = (w - cj[j]*xpv) / n1;
          s1[j*HID + idx] = w;
          ua[j] += xnv*w;
          m1s += w*w;
        }
      }
      #pragma unroll
      for (int j = 0; j < CW; j++){
        float v = wredf(ua[j]);
        if ((tid & 63) == 0) ascr[(tid >> 6)*CW + j] = v;
      }
      m1s = wredf(m1s);
      if ((tid & 63) == 0) ascr[32 + (tid >> 6)] = m1s;
    }
    __syncthreads();
    if (tid < CW){
      float s = 0.f;
      for (int w = 0; w < 8; w++) s += ascr[w*CW + tid];
      dstore(&U[wg*CW + tid], s);
    }
    if (tid == 0){
      float m1 = 0.f; for (int w = 0; w < 8; w++) m1 += ascr[32 + w];
      unsafeAtomicAdd(&AC[(p*16 + bank)*8 + 0], m1);
    }
    gsync(arrive, release, ep++, wg);   // syncQ: o1 partials published

    // ================= Phase C: reduce o1, zero next-parity accumulators ========
    {
      int c = tid >> 7, l = tid & 127;
      int col = wg*CW + c;
      float s = dload(&QP[(size_t)l*HID + col]) + dload(&QP[(size_t)(l + 128)*HID + col]);
      s = wredf(s);
      int wid = tid >> 6;
      if ((tid & 63) == 0) ascr[wid] = s;
    }
    __syncthreads();
    if (tid < CW) dstore(&O1R[wg*CW + tid], ascr[2*tid] + ascr[2*tid + 1]);
    if (wg < 16){
      if (tid < OUTD) dstore(&P3[(qq*16 + wg)*OUTD + tid], 0.f);
      if (tid < 8)    dstore(&AC[(qq*16 + wg)*8 + tid], 0.f);
    }
    gsync(arrive, release, ep++, wg);   // syncU: o1 ready
  }
}

extern "C" void kernel_launch(void* const* d_in, const int* in_sizes, int n_in,
                              void* d_out, int out_size, void* d_ws, size_t ws_size,
                              hipStream_t stream){
  const float* x  = (const float*)d_in[0];
  const float* tg = (const float*)d_in[1];
  const float* w1 = (const float*)d_in[2];
  const float* b1 = (const float*)d_in[3];
  const float* w2 = (const float*)d_in[4];
  const float* b2 = (const float*)d_in[5];
  const float* w3 = (const float*)d_in[6];
  const float* b3 = (const float*)d_in[7];
  float* out = (float*)d_out;
  float* wsf = (float*)d_ws;
  hipLaunchKernelGGL(bp_init,  dim3(NSTEP), dim3(64),  0, stream, x, wsf);
  hipLaunchKernelGGL(bp_train, dim3(NWG),   dim3(TPB), 0, stream,
                     x, tg, w1, b1, w2, b2, w3, b3, out, wsf);
}